// Round 1
// baseline (1088.876 us; speedup 1.0000x reference)
//
#include <hip/hip_runtime.h>
#include <cmath>

// ---------------------------------------------------------------------------
// CrossAttention (segment softmax attention pooling), algebraically reduced:
//   s_n   = key_n . qk[b]  + c[b],   qk[b] = scale * Wk^T (Wq q_b + bq)
//   vsum_b = sum_n e_n * value_n,    denom_b = sum_n e_n   (online softmax)
//   out_b = ((Wv vsum_b)/denom_b + bv) @ Wo^T + bo          (denom>0)
// Heavy pass reads key+value exactly once: 1.07 GB -> HBM-bound ~170us floor.
// ---------------------------------------------------------------------------

__global__ __launch_bounds__(256) void prep_transpose(
    const float* __restrict__ Wq, const float* __restrict__ Wv,
    const float* __restrict__ Wo, float* __restrict__ WqT,
    float* __restrict__ WvT, float* __restrict__ WoT) {
  int idx = blockIdx.x * 256 + threadIdx.x;
  if (idx < 128 * 128) {
    int d = idx >> 7, j = idx & 127;
    WqT[j * 128 + d] = Wq[idx];
    WoT[j * 128 + d] = Wo[idx];
  }
  if (idx < 128 * 256) {
    int d = idx >> 8, h = idx & 255;
    WvT[h * 128 + d] = Wv[idx];
  }
}

__global__ __launch_bounds__(256) void starts_kernel(
    const int* __restrict__ batch, int N, int B, int* __restrict__ starts) {
  int b = blockIdx.x * 256 + threadIdx.x;
  if (b > B) return;
  int lo = 0, hi = N;
  while (lo < hi) {
    int mid = (lo + hi) >> 1;
    if (batch[mid] < b) lo = mid + 1; else hi = mid;
  }
  starts[b] = lo;  // first index with batch[i] >= b ; starts[B] = N
}

// qk[b,h] = scale * sum_d Wk[d,h] * q[b,d],  q = query@WqT(+bq),  c[b]=scale*q.bk
// 8 graphs per block for weight-traffic reuse.
__global__ __launch_bounds__(256) void qk_kernel(
    const float* __restrict__ query, const float* __restrict__ WqT,
    const float* __restrict__ bq, const float* __restrict__ Wk,
    const float* __restrict__ bk, float* __restrict__ qk,
    float* __restrict__ cvec, float scale) {
  __shared__ float query_s[8][128];
  __shared__ float q_s[8][128];
  const int t = threadIdx.x;
  const int g0 = blockIdx.x * 8;

#pragma unroll
  for (int k2 = 0; k2 < 4; ++k2) {
    int idx = k2 * 256 + t;
    query_s[idx >> 7][idx & 127] = query[(size_t)g0 * 128 + idx];
  }
  __syncthreads();

  {  // phase 1: q_s[gg][d] = bq[d] + query_s[gg][:] . WqT[:,d]
    const int d = t & 127;
    const int gb = (t >> 7) * 4;  // 0 or 4
    float a0 = bq[d], a1 = a0, a2 = a0, a3 = a0;
    for (int j = 0; j < 128; ++j) {
      float w = WqT[j * 128 + d];
      a0 += w * query_s[gb + 0][j];
      a1 += w * query_s[gb + 1][j];
      a2 += w * query_s[gb + 2][j];
      a3 += w * query_s[gb + 3][j];
    }
    q_s[gb + 0][d] = a0; q_s[gb + 1][d] = a1;
    q_s[gb + 2][d] = a2; q_s[gb + 3][d] = a3;
  }
  __syncthreads();

  if (t < 8) {  // c[g] = scale * q . bk
    float acc = 0.f;
    for (int d = 0; d < 128; ++d) acc += q_s[t][d] * bk[d];
    cvec[g0 + t] = scale * acc;
  }

  {  // phase 2: qk[gg][h] for h = t
    float acc[8];
#pragma unroll
    for (int i = 0; i < 8; ++i) acc[i] = 0.f;
    for (int d = 0; d < 128; ++d) {
      float w = Wk[d * 256 + t];
#pragma unroll
      for (int i = 0; i < 8; ++i) acc[i] += w * q_s[i][d];
    }
#pragma unroll
    for (int i = 0; i < 8; ++i) qk[(size_t)(g0 + i) * 256 + t] = scale * acc[i];
  }
}

// Main fused pass: one 64-lane wave per graph, online softmax over its
// contiguous node range. Lane l owns components 4l..4l+3 (float4).
__global__ __launch_bounds__(256) void attn_main(
    const float* __restrict__ key, const float* __restrict__ value,
    const int* __restrict__ starts, const float* __restrict__ qk,
    const float* __restrict__ cvec, float* __restrict__ vsum,
    float* __restrict__ denom) {
  const int lane = threadIdx.x & 63;
  const int g = blockIdx.x * 4 + (threadIdx.x >> 6);

  const float4 qv = ((const float4*)(qk + (size_t)g * 256))[lane];
  const float cb = cvec[g];
  const int n0 = starts[g], n1 = starts[g + 1];

  float m = -INFINITY;
  float den = 0.f;
  float4 vs = make_float4(0.f, 0.f, 0.f, 0.f);

  for (int n = n0; n < n1; ++n) {
    const float4 kv = ((const float4*)(key + (size_t)n * 256))[lane];
    const float4 vv = ((const float4*)(value + (size_t)n * 256))[lane];
    float p = kv.x * qv.x + kv.y * qv.y + kv.z * qv.z + kv.w * qv.w;
#pragma unroll
    for (int off = 32; off; off >>= 1) p += __shfl_xor(p, off, 64);
    const float s = p + cb;  // wave-uniform
    if (s <= m) {            // common path: max unchanged, no rescale
      const float e = __expf(s - m);
      den += e;
      vs.x += e * vv.x; vs.y += e * vv.y; vs.z += e * vv.z; vs.w += e * vv.w;
    } else {                 // new max (also handles first node: exp(-inf)=0)
      const float al = __expf(m - s);
      den = den * al + 1.f;
      vs.x = vs.x * al + vv.x; vs.y = vs.y * al + vv.y;
      vs.z = vs.z * al + vv.z; vs.w = vs.w * al + vv.w;
      m = s;
    }
  }

  ((float4*)(vsum + (size_t)g * 256))[lane] = vs;
  if (lane == 0) denom[g] = den;
}

// Epilogue: out = ((Wv vsum)/denom + bv) @ Wo^T + bo ; 8 graphs per block.
__global__ __launch_bounds__(256) void final_kernel(
    const float* __restrict__ vsum, const float* __restrict__ denom,
    const float* __restrict__ WvT, const float* __restrict__ bv,
    const float* __restrict__ WoT, const float* __restrict__ bo,
    float* __restrict__ out) {
  __shared__ float vs_s[8][256];
  __shared__ float avg_s[8][128];
  __shared__ float den_s[8];
  const int t = threadIdx.x;
  const int g0 = blockIdx.x * 8;

#pragma unroll
  for (int k2 = 0; k2 < 8; ++k2) {
    int idx = k2 * 256 + t;
    vs_s[idx >> 8][idx & 255] = vsum[(size_t)g0 * 256 + idx];
  }
  if (t < 8) den_s[t] = denom[g0 + t];
  __syncthreads();

  {  // avg[gg][d] = (WvT[:,d].vsum[gg])/den + bv[d]   (0 if den<=0)
    const int d = t & 127;
    const int gb = (t >> 7) * 4;
    float a0 = 0.f, a1 = 0.f, a2 = 0.f, a3 = 0.f;
    for (int h = 0; h < 256; ++h) {
      float w = WvT[h * 128 + d];
      a0 += w * vs_s[gb + 0][h];
      a1 += w * vs_s[gb + 1][h];
      a2 += w * vs_s[gb + 2][h];
      a3 += w * vs_s[gb + 3][h];
    }
    float bvd = bv[d], dn;
    dn = den_s[gb + 0]; avg_s[gb + 0][d] = dn > 0.f ? a0 / dn + bvd : 0.f;
    dn = den_s[gb + 1]; avg_s[gb + 1][d] = dn > 0.f ? a1 / dn + bvd : 0.f;
    dn = den_s[gb + 2]; avg_s[gb + 2][d] = dn > 0.f ? a2 / dn + bvd : 0.f;
    dn = den_s[gb + 3]; avg_s[gb + 3][d] = dn > 0.f ? a3 / dn + bvd : 0.f;
  }
  __syncthreads();

  {  // out[gg][o] = bo[o] + WoT[:,o] . avg[gg]
    const int o = t & 127;
    const int gb = (t >> 7) * 4;
    float b = bo[o];
    float a0 = b, a1 = b, a2 = b, a3 = b;
    for (int d = 0; d < 128; ++d) {
      float w = WoT[d * 128 + o];
      a0 += w * avg_s[gb + 0][d];
      a1 += w * avg_s[gb + 1][d];
      a2 += w * avg_s[gb + 2][d];
      a3 += w * avg_s[gb + 3][d];
    }
    out[(size_t)(g0 + gb + 0) * 128 + o] = a0;
    out[(size_t)(g0 + gb + 1) * 128 + o] = a1;
    out[(size_t)(g0 + gb + 2) * 128 + o] = a2;
    out[(size_t)(g0 + gb + 3) * 128 + o] = a3;
  }
}

extern "C" void kernel_launch(void* const* d_in, const int* in_sizes, int n_in,
                              void* d_out, int out_size, void* d_ws, size_t ws_size,
                              hipStream_t stream) {
  const float* query = (const float*)d_in[0];
  const float* key   = (const float*)d_in[1];
  const float* value = (const float*)d_in[2];
  const int*   batch = (const int*)d_in[3];
  const float* Wq = (const float*)d_in[4];
  const float* bq = (const float*)d_in[5];
  const float* Wk = (const float*)d_in[6];
  const float* bk = (const float*)d_in[7];
  const float* Wv = (const float*)d_in[8];
  const float* bv = (const float*)d_in[9];
  const float* Wo = (const float*)d_in[10];
  const float* bo = (const float*)d_in[11];
  float* out = (float*)d_out;

  const int B = in_sizes[0] / 128;  // 8192
  const int N = in_sizes[3];        // 524288
  const float scale = 0.08838834764831845f;  // 1/sqrt(128)

  char* ws = (char*)d_ws;
  size_t off = 0;
  auto take = [&](size_t bytes) {
    char* p = ws + off;
    off = (off + bytes + 255) & ~(size_t)255;
    return p;
  };
  int*   starts = (int*)  take((size_t)(B + 1) * 4);
  float* qk     = (float*)take((size_t)B * 256 * 4);
  float* cvec   = (float*)take((size_t)B * 4);
  float* vsum   = (float*)take((size_t)B * 256 * 4);
  float* denom  = (float*)take((size_t)B * 4);
  float* WqT    = (float*)take((size_t)128 * 128 * 4);
  float* WvT    = (float*)take((size_t)256 * 128 * 4);
  float* WoT    = (float*)take((size_t)128 * 128 * 4);
  (void)ws_size; (void)n_in; (void)out_size;

  hipLaunchKernelGGL(prep_transpose, dim3(128), dim3(256), 0, stream,
                     Wq, Wv, Wo, WqT, WvT, WoT);
  hipLaunchKernelGGL(starts_kernel, dim3((B + 1 + 255) / 256), dim3(256), 0, stream,
                     batch, N, B, starts);
  hipLaunchKernelGGL(qk_kernel, dim3(B / 8), dim3(256), 0, stream,
                     query, WqT, bq, Wk, bk, qk, cvec, scale);
  hipLaunchKernelGGL(attn_main, dim3(B / 4), dim3(256), 0, stream,
                     key, value, starts, qk, cvec, vsum, denom);
  hipLaunchKernelGGL(final_kernel, dim3(B / 8), dim3(256), 0, stream,
                     vsum, denom, WvT, bv, WoT, bo, out);
}

// Round 2
// 1064.563 us; speedup vs baseline: 1.0228x; 1.0228x over previous
//
#include <hip/hip_runtime.h>
#include <cmath>

// ---------------------------------------------------------------------------
// CrossAttention (segment softmax attention pooling), algebraically reduced:
//   s_n   = key_n . qk[b]  + c[b],   qk[b] = scale * Wk^T (Wq q_b + bq)
//   vsum_b = sum_n e_n * value_n,    denom_b = sum_n e_n   (online softmax)
//   out_b = ((Wv vsum_b)/denom_b + bv) @ Wo^T + bo          (denom>0)
// Heavy pass reads key+value exactly once: 1.07 GB -> HBM-bound ~170us floor.
// attn_main: batch-4 branchless online softmax, transposed shuffle reduce,
// explicit next-batch prefetch (8 nt-dwordx4 in flight per wave).
// ---------------------------------------------------------------------------

typedef float vf4 __attribute__((ext_vector_type(4)));

__global__ __launch_bounds__(256) void prep_transpose(
    const float* __restrict__ Wq, const float* __restrict__ Wv,
    const float* __restrict__ Wo, float* __restrict__ WqT,
    float* __restrict__ WvT, float* __restrict__ WoT) {
  int idx = blockIdx.x * 256 + threadIdx.x;
  if (idx < 128 * 128) {
    int d = idx >> 7, j = idx & 127;
    WqT[j * 128 + d] = Wq[idx];
    WoT[j * 128 + d] = Wo[idx];
  }
  if (idx < 128 * 256) {
    int d = idx >> 8, h = idx & 255;
    WvT[h * 128 + d] = Wv[idx];
  }
}

__global__ __launch_bounds__(256) void starts_kernel(
    const int* __restrict__ batch, int N, int B, int* __restrict__ starts) {
  int b = blockIdx.x * 256 + threadIdx.x;
  if (b > B) return;
  int lo = 0, hi = N;
  while (lo < hi) {
    int mid = (lo + hi) >> 1;
    if (batch[mid] < b) lo = mid + 1; else hi = mid;
  }
  starts[b] = lo;  // first index with batch[i] >= b ; starts[B] = N
}

// qk[b,h] = scale * sum_d Wk[d,h] * q[b,d],  q = query@WqT(+bq),  c[b]=scale*q.bk
__global__ __launch_bounds__(256) void qk_kernel(
    const float* __restrict__ query, const float* __restrict__ WqT,
    const float* __restrict__ bq, const float* __restrict__ Wk,
    const float* __restrict__ bk, float* __restrict__ qk,
    float* __restrict__ cvec, float scale) {
  __shared__ float query_s[8][128];
  __shared__ float q_s[8][128];
  const int t = threadIdx.x;
  const int g0 = blockIdx.x * 8;

#pragma unroll
  for (int k2 = 0; k2 < 4; ++k2) {
    int idx = k2 * 256 + t;
    query_s[idx >> 7][idx & 127] = query[(size_t)g0 * 128 + idx];
  }
  __syncthreads();

  {  // phase 1: q_s[gg][d] = bq[d] + query_s[gg][:] . WqT[:,d]
    const int d = t & 127;
    const int gb = (t >> 7) * 4;  // 0 or 4
    float a0 = bq[d], a1 = a0, a2 = a0, a3 = a0;
    for (int j = 0; j < 128; ++j) {
      float w = WqT[j * 128 + d];
      a0 += w * query_s[gb + 0][j];
      a1 += w * query_s[gb + 1][j];
      a2 += w * query_s[gb + 2][j];
      a3 += w * query_s[gb + 3][j];
    }
    q_s[gb + 0][d] = a0; q_s[gb + 1][d] = a1;
    q_s[gb + 2][d] = a2; q_s[gb + 3][d] = a3;
  }
  __syncthreads();

  if (t < 8) {  // c[g] = scale * q . bk
    float acc = 0.f;
    for (int d = 0; d < 128; ++d) acc += q_s[t][d] * bk[d];
    cvec[g0 + t] = scale * acc;
  }

  {  // phase 2: qk[gg][h] for h = t
    float acc[8];
#pragma unroll
    for (int i = 0; i < 8; ++i) acc[i] = 0.f;
    for (int d = 0; d < 128; ++d) {
      float w = Wk[d * 256 + t];
#pragma unroll
      for (int i = 0; i < 8; ++i) acc[i] += w * q_s[i][d];
    }
#pragma unroll
    for (int i = 0; i < 8; ++i) qk[(size_t)(g0 + i) * 256 + t] = scale * acc[i];
  }
}

// Main fused pass: one 64-lane wave per graph, online softmax over its
// contiguous node range. Lane l owns components 4l..4l+3 (float4).
// Batch-4 branchless; transposed 11-shuffle reduce for 4 scores; explicit
// next-batch prefetch so 8 KB/wave stays in flight.
__global__ __launch_bounds__(256) void attn_main(
    const float* __restrict__ key, const float* __restrict__ value,
    const int* __restrict__ starts, const float* __restrict__ qk,
    const float* __restrict__ cvec, float* __restrict__ vsum,
    float* __restrict__ denom) {
  const int lane = threadIdx.x & 63;
  const int g = blockIdx.x * 4 + (threadIdx.x >> 6);

  const vf4 qv = ((const vf4*)(qk + (size_t)g * 256))[lane];
  const float cb = cvec[g];
  const int n0 = starts[g], n1 = starts[g + 1];
  const int cnt = n1 - n0;
  const int nb = cnt >> 2;  // number of 4-node batches

  float m = -INFINITY;
  float den = 0.f;
  vf4 vs = {0.f, 0.f, 0.f, 0.f};

  const vf4* kp = (const vf4*)key + (size_t)n0 * 64 + lane;    // 64 vf4 / node
  const vf4* vp = (const vf4*)value + (size_t)n0 * 64 + lane;

  vf4 k0, k1, k2, k3, v0, v1, v2, v3;

  auto process = [&](vf4 a0, vf4 a1, vf4 a2, vf4 a3,
                     vf4 w0, vf4 w1, vf4 w2, vf4 w3) {
    float p0 = a0.x * qv.x + a0.y * qv.y + a0.z * qv.z + a0.w * qv.w;
    float p1 = a1.x * qv.x + a1.y * qv.y + a1.z * qv.z + a1.w * qv.w;
    float p2 = a2.x * qv.x + a2.y * qv.y + a2.z * qv.z + a2.w * qv.w;
    float p3 = a3.x * qv.x + a3.y * qv.y + a3.z * qv.z + a3.w * qv.w;
    // transposed reduce: round A (xor 1) pairs (p0,p1),(p2,p3)
    const bool b0 = lane & 1;
    float u0 = (b0 ? p1 : p0) + __shfl_xor(b0 ? p0 : p1, 1, 64);
    float u1 = (b0 ? p3 : p2) + __shfl_xor(b0 ? p2 : p3, 1, 64);
    // round B (xor 2): pair (u0,u1) -> x holds array (lane&3)
    const bool b1 = lane & 2;
    float x = (b1 ? u1 : u0) + __shfl_xor(b1 ? u0 : u1, 2, 64);
    x += __shfl_xor(x, 4, 64);
    x += __shfl_xor(x, 8, 64);
    x += __shfl_xor(x, 16, 64);
    x += __shfl_xor(x, 32, 64);
    // lane i (i<4) now holds full sum of node i; broadcast all 4
    const float s0 = __shfl(x, 0, 64) + cb;
    const float s1 = __shfl(x, 1, 64) + cb;
    const float s2 = __shfl(x, 2, 64) + cb;
    const float s3 = __shfl(x, 3, 64) + cb;
    const float M = fmaxf(fmaxf(fmaxf(s0, s1), fmaxf(s2, s3)), m);
    const float al = __expf(m - M);  // m=-inf first batch -> al=0
    const float e0 = __expf(s0 - M);
    const float e1 = __expf(s1 - M);
    const float e2 = __expf(s2 - M);
    const float e3 = __expf(s3 - M);
    m = M;
    den = den * al + ((e0 + e1) + (e2 + e3));
    vs.x = vs.x * al + e0 * w0.x + e1 * w1.x + e2 * w2.x + e3 * w3.x;
    vs.y = vs.y * al + e0 * w0.y + e1 * w1.y + e2 * w2.y + e3 * w3.y;
    vs.z = vs.z * al + e0 * w0.z + e1 * w1.z + e2 * w2.z + e3 * w3.z;
    vs.w = vs.w * al + e0 * w0.w + e1 * w1.w + e2 * w2.w + e3 * w3.w;
  };

  if (nb > 0) {
    k0 = __builtin_nontemporal_load(kp);
    k1 = __builtin_nontemporal_load(kp + 64);
    k2 = __builtin_nontemporal_load(kp + 128);
    k3 = __builtin_nontemporal_load(kp + 192);
    v0 = __builtin_nontemporal_load(vp);
    v1 = __builtin_nontemporal_load(vp + 64);
    v2 = __builtin_nontemporal_load(vp + 128);
    v3 = __builtin_nontemporal_load(vp + 192);
    for (int b = 0; b + 1 < nb; ++b) {
      kp += 256; vp += 256;
      vf4 nk0 = __builtin_nontemporal_load(kp);
      vf4 nk1 = __builtin_nontemporal_load(kp + 64);
      vf4 nk2 = __builtin_nontemporal_load(kp + 128);
      vf4 nk3 = __builtin_nontemporal_load(kp + 192);
      vf4 nv0 = __builtin_nontemporal_load(vp);
      vf4 nv1 = __builtin_nontemporal_load(vp + 64);
      vf4 nv2 = __builtin_nontemporal_load(vp + 128);
      vf4 nv3 = __builtin_nontemporal_load(vp + 192);
      process(k0, k1, k2, k3, v0, v1, v2, v3);
      k0 = nk0; k1 = nk1; k2 = nk2; k3 = nk3;
      v0 = nv0; v1 = nv1; v2 = nv2; v3 = nv3;
    }
    process(k0, k1, k2, k3, v0, v1, v2, v3);
  }

  // tail: up to 3 single nodes
  for (int n = n0 + (nb << 2); n < n1; ++n) {
    const vf4 kv = __builtin_nontemporal_load((const vf4*)key + (size_t)n * 64 + lane);
    const vf4 vv = __builtin_nontemporal_load((const vf4*)value + (size_t)n * 64 + lane);
    float p = kv.x * qv.x + kv.y * qv.y + kv.z * qv.z + kv.w * qv.w;
#pragma unroll
    for (int off = 32; off; off >>= 1) p += __shfl_xor(p, off, 64);
    const float s = p + cb;
    const float M = fmaxf(m, s);
    const float al = __expf(m - M);
    const float e = __expf(s - M);
    m = M;
    den = den * al + e;
    vs.x = vs.x * al + e * vv.x;
    vs.y = vs.y * al + e * vv.y;
    vs.z = vs.z * al + e * vv.z;
    vs.w = vs.w * al + e * vv.w;
  }

  ((vf4*)(vsum + (size_t)g * 256))[lane] = vs;
  if (lane == 0) denom[g] = den;
}

// Epilogue: out = ((Wv vsum)/denom + bv) @ Wo^T + bo ; 8 graphs per block.
__global__ __launch_bounds__(256) void final_kernel(
    const float* __restrict__ vsum, const float* __restrict__ denom,
    const float* __restrict__ WvT, const float* __restrict__ bv,
    const float* __restrict__ WoT, const float* __restrict__ bo,
    float* __restrict__ out) {
  __shared__ float vs_s[8][256];
  __shared__ float avg_s[8][128];
  __shared__ float den_s[8];
  const int t = threadIdx.x;
  const int g0 = blockIdx.x * 8;

#pragma unroll
  for (int k2 = 0; k2 < 8; ++k2) {
    int idx = k2 * 256 + t;
    vs_s[idx >> 8][idx & 255] = vsum[(size_t)g0 * 256 + idx];
  }
  if (t < 8) den_s[t] = denom[g0 + t];
  __syncthreads();

  {  // avg[gg][d] = (WvT[:,d].vsum[gg])/den + bv[d]   (0 if den<=0)
    const int d = t & 127;
    const int gb = (t >> 7) * 4;
    float a0 = 0.f, a1 = 0.f, a2 = 0.f, a3 = 0.f;
    for (int h = 0; h < 256; ++h) {
      float w = WvT[h * 128 + d];
      a0 += w * vs_s[gb + 0][h];
      a1 += w * vs_s[gb + 1][h];
      a2 += w * vs_s[gb + 2][h];
      a3 += w * vs_s[gb + 3][h];
    }
    float bvd = bv[d], dn;
    dn = den_s[gb + 0]; avg_s[gb + 0][d] = dn > 0.f ? a0 / dn + bvd : 0.f;
    dn = den_s[gb + 1]; avg_s[gb + 1][d] = dn > 0.f ? a1 / dn + bvd : 0.f;
    dn = den_s[gb + 2]; avg_s[gb + 2][d] = dn > 0.f ? a2 / dn + bvd : 0.f;
    dn = den_s[gb + 3]; avg_s[gb + 3][d] = dn > 0.f ? a3 / dn + bvd : 0.f;
  }
  __syncthreads();

  {  // out[gg][o] = bo[o] + WoT[:,o] . avg[gg]
    const int o = t & 127;
    const int gb = (t >> 7) * 4;
    float b = bo[o];
    float a0 = b, a1 = b, a2 = b, a3 = b;
    for (int d = 0; d < 128; ++d) {
      float w = WoT[d * 128 + o];
      a0 += w * avg_s[gb + 0][d];
      a1 += w * avg_s[gb + 1][d];
      a2 += w * avg_s[gb + 2][d];
      a3 += w * avg_s[gb + 3][d];
    }
    out[(size_t)(g0 + gb + 0) * 128 + o] = a0;
    out[(size_t)(g0 + gb + 1) * 128 + o] = a1;
    out[(size_t)(g0 + gb + 2) * 128 + o] = a2;
    out[(size_t)(g0 + gb + 3) * 128 + o] = a3;
  }
}

extern "C" void kernel_launch(void* const* d_in, const int* in_sizes, int n_in,
                              void* d_out, int out_size, void* d_ws, size_t ws_size,
                              hipStream_t stream) {
  const float* query = (const float*)d_in[0];
  const float* key   = (const float*)d_in[1];
  const float* value = (const float*)d_in[2];
  const int*   batch = (const int*)d_in[3];
  const float* Wq = (const float*)d_in[4];
  const float* bq = (const float*)d_in[5];
  const float* Wk = (const float*)d_in[6];
  const float* bk = (const float*)d_in[7];
  const float* Wv = (const float*)d_in[8];
  const float* bv = (const float*)d_in[9];
  const float* Wo = (const float*)d_in[10];
  const float* bo = (const float*)d_in[11];
  float* out = (float*)d_out;

  const int B = in_sizes[0] / 128;  // 8192
  const int N = in_sizes[3];        // 524288
  const float scale = 0.08838834764831845f;  // 1/sqrt(128)

  char* ws = (char*)d_ws;
  size_t off = 0;
  auto take = [&](size_t bytes) {
    char* p = ws + off;
    off = (off + bytes + 255) & ~(size_t)255;
    return p;
  };
  int*   starts = (int*)  take((size_t)(B + 1) * 4);
  float* qk     = (float*)take((size_t)B * 256 * 4);
  float* cvec   = (float*)take((size_t)B * 4);
  float* vsum   = (float*)take((size_t)B * 256 * 4);
  float* denom  = (float*)take((size_t)B * 4);
  float* WqT    = (float*)take((size_t)128 * 128 * 4);
  float* WvT    = (float*)take((size_t)256 * 128 * 4);
  float* WoT    = (float*)take((size_t)128 * 128 * 4);
  (void)ws_size; (void)n_in; (void)out_size;

  hipLaunchKernelGGL(prep_transpose, dim3(128), dim3(256), 0, stream,
                     Wq, Wv, Wo, WqT, WvT, WoT);
  hipLaunchKernelGGL(starts_kernel, dim3((B + 1 + 255) / 256), dim3(256), 0, stream,
                     batch, N, B, starts);
  hipLaunchKernelGGL(qk_kernel, dim3(B / 8), dim3(256), 0, stream,
                     query, WqT, bq, Wk, bk, qk, cvec, scale);
  hipLaunchKernelGGL(attn_main, dim3(B / 4), dim3(256), 0, stream,
                     key, value, starts, qk, cvec, vsum, denom);
  hipLaunchKernelGGL(final_kernel, dim3(B / 8), dim3(256), 0, stream,
                     vsum, denom, WvT, bv, WoT, bo, out);
}